// Round 3
// baseline (961.187 us; speedup 1.0000x reference)
//
#include <hip/hip_runtime.h>
#include <stdint.h>

// Problem constants (B=4, S=2048 -> T=8192 tokens)
#define T_TOK 8192
#define DIM   1024
#define NEXP  8
#define HID   2816

typedef __bf16 bf16x8 __attribute__((ext_vector_type(8)));
typedef float  f32x4  __attribute__((ext_vector_type(4)));

typedef __attribute__((address_space(3))) uint32_t lds_u32_t;
typedef __attribute__((address_space(1))) const uint32_t gbl_u32_t;

// async global->LDS, 16B per lane. LDS dest = wave-uniform base + lane*16.
__device__ __forceinline__ void gl_lds16(const void* g, void* l) {
    __builtin_amdgcn_global_load_lds((gbl_u32_t*)g, (lds_u32_t*)l, 16, 0, 0);
}

__device__ __forceinline__ uint32_t f2bf_u(float f) {
    uint32_t u = __builtin_bit_cast(uint32_t, f);
    return u + 0x7fffu + ((u >> 16) & 1u);   // RNE to bf16, top 16 bits valid
}
__device__ __forceinline__ uint32_t pack2(float a, float b) {
    return (f2bf_u(a) >> 16) | (f2bf_u(b) & 0xffff0000u);
}

// ---------------------------------------------------------------------------
// fp32 -> bf16 conversion kernels. cvt_k: single tensor. cvt3_k: 3 weights.
// ---------------------------------------------------------------------------
__global__ __launch_bounds__(256) void cvt_k(
    const float* __restrict__ s, unsigned short* __restrict__ d, int n8)
{
    int i = blockIdx.x * 256 + threadIdx.x;
    if (i < n8) {
        const float4* sp = (const float4*)(s + (size_t)i * 8);
        float4 a = sp[0], b = sp[1];
        uint4 o;
        o.x = pack2(a.x, a.y); o.y = pack2(a.z, a.w);
        o.z = pack2(b.x, b.y); o.w = pack2(b.z, b.w);
        ((uint4*)d)[i] = o;
    }
}

__global__ __launch_bounds__(256) void cvt3_k(
    const float* __restrict__ s1, const float* __restrict__ s3,
    const float* __restrict__ s2, unsigned short* __restrict__ d1,
    unsigned short* __restrict__ d3, unsigned short* __restrict__ d2, int n8)
{
    int i = blockIdx.x * 256 + threadIdx.x;
    if (i >= n8) return;
    const float* s; unsigned short* d;
    if (blockIdx.y == 0)      { s = s1; d = d1; }
    else if (blockIdx.y == 1) { s = s3; d = d3; }
    else                      { s = s2; d = d2; }
    const float4* sp = (const float4*)(s + (size_t)i * 8);
    float4 a = sp[0], b = sp[1];
    uint4 o;
    o.x = pack2(a.x, a.y); o.y = pack2(a.z, a.w);
    o.z = pack2(b.x, b.y); o.w = pack2(b.z, b.w);
    ((uint4*)d)[i] = o;
}

// ---------------------------------------------------------------------------
// Router: one wave per token, fp64 logits, top-2 + softmax, gather lists.
// ---------------------------------------------------------------------------
__global__ __launch_bounds__(256) void router_k(
    const float* __restrict__ x, const float* __restrict__ gw,
    int* __restrict__ cnt, int* __restrict__ slot_list,
    float* __restrict__ slot_w)
{
    const int wave = threadIdx.x >> 6, lane = threadIdx.x & 63;
    const int t = blockIdx.x * 4 + wave;
    const float4* xp = (const float4*)(x + (size_t)t * DIM + lane * 16);
    float4 xv[4];
#pragma unroll
    for (int i = 0; i < 4; ++i) xv[i] = xp[i];

    double lg[NEXP];
#pragma unroll
    for (int e = 0; e < NEXP; ++e) {
        const float4* gp = (const float4*)(gw + (size_t)e * DIM + lane * 16);
        double s = 0.0;
#pragma unroll
        for (int i = 0; i < 4; ++i) {
            float4 g = gp[i];
            s += (double)xv[i].x * g.x + (double)xv[i].y * g.y +
                 (double)xv[i].z * g.z + (double)xv[i].w * g.w;
        }
#pragma unroll
        for (int m = 32; m >= 1; m >>= 1) s += __shfl_xor(s, m, 64);
        lg[e] = s;
    }

    if (lane == 0) {
        int e0 = 0; double b0 = lg[0];
#pragma unroll
        for (int e = 1; e < NEXP; ++e)
            if (lg[e] > b0) { b0 = lg[e]; e0 = e; }
        int e1 = -1; double b1 = -1.0e300;
#pragma unroll
        for (int e = 0; e < NEXP; ++e)
            if (e != e0 && lg[e] > b1) { b1 = lg[e]; e1 = e; }

        float p0 = (float)(1.0 / (1.0 + exp(b1 - b0)));
        float p1 = 1.0f - p0;

        int pos0 = atomicAdd(&cnt[e0], 1);
        slot_list[e0 * T_TOK + pos0] = 2 * t;
        slot_w[2 * t] = p0;
        int pos1 = atomicAdd(&cnt[e1], 1);
        slot_list[e1 * T_TOK + pos1] = 2 * t + 1;
        slot_w[2 * t + 1] = p1;
    }
}

// ---------------------------------------------------------------------------
// ffn1: gathered GEMM, fused w1/w3 + SwiGLU. BK=64, swizzled LDS layout:
// LDS(row, 16B-quarter q) holds global quarter (q ^ (row&7)) -> bank-conflict
// free fragment reads while global_load_lds keeps its identity lane scatter.
// C-tile 128 slots x (64+64) hid. grid (44, 64, 8).
// ---------------------------------------------------------------------------
__global__ __launch_bounds__(256) void ffn1_k(
    const unsigned short* __restrict__ xb, const unsigned short* __restrict__ w1b,
    const unsigned short* __restrict__ w3b, const int* __restrict__ cnt,
    const int* __restrict__ slot_list, unsigned short* __restrict__ h_ws)
{
    __shared__ unsigned short As[128 * 64];
    __shared__ unsigned short B1s[64 * 64];
    __shared__ unsigned short B2s[64 * 64];
    __shared__ int slots_s[128];

    const int e = blockIdx.z;
    const int cntE = cnt[e];
    const int m0 = blockIdx.y * 128;
    if (m0 >= cntE) return;
    const int n0 = blockIdx.x * 64;
    const int tid = threadIdx.x;
    const int wave = tid >> 6, lane = tid & 63;

    if (tid < 128) {
        int idx = m0 + tid;
        slots_s[tid] = (idx < cntE) ? slot_list[e * T_TOK + idx] : -1;
    }
    __syncthreads();

    // staging: 8 gl_lds16 per wave per K-tile (8 rows x 128B each).
    const int sub = lane >> 3;          // row within 8-row instruction
    const int kq  = lane & 7;           // 16B quarter within 128B row
    const int qg  = kq ^ sub;           // swizzled global quarter
    const unsigned short* gsrc[8];
    unsigned short* ldst[8];
    if (wave < 2) {
#pragma unroll
        for (int i = 0; i < 8; ++i) {
            int row = wave * 64 + i * 8 + sub;
            int slot = slots_s[row];
            int tok = (slot >= 0) ? (slot >> 1) : 0;
            gsrc[i] = xb + (size_t)tok * DIM + qg * 8;
            ldst[i] = &As[(wave * 64 + i * 8) * 64];
        }
    } else if (wave == 2) {
#pragma unroll
        for (int i = 0; i < 8; ++i) {
            int row = i * 8 + sub;
            gsrc[i] = w1b + ((size_t)e * HID + n0 + row) * DIM + qg * 8;
            ldst[i] = &B1s[(i * 8) * 64];
        }
    } else {
#pragma unroll
        for (int i = 0; i < 8; ++i) {
            int row = i * 8 + sub;
            gsrc[i] = w3b + ((size_t)e * HID + n0 + row) * DIM + qg * 8;
            ldst[i] = &B2s[(i * 8) * 64];
        }
    }

    const int wm = wave >> 1, wn = wave & 1;
    const int lrow = lane & 15, quad = lane >> 4;
    const int s_r = lrow & 7;
    const int ko[2] = { (quad ^ s_r) * 8, ((quad | 4) ^ s_r) * 8 };

    f32x4 acc1[4][2], acc2[4][2];
    const f32x4 zf = {0.f, 0.f, 0.f, 0.f};
#pragma unroll
    for (int mi = 0; mi < 4; ++mi)
#pragma unroll
        for (int ni = 0; ni < 2; ++ni) { acc1[mi][ni] = zf; acc2[mi][ni] = zf; }

    for (int k0 = 0; k0 < DIM; k0 += 64) {
#pragma unroll
        for (int i = 0; i < 8; ++i) gl_lds16(gsrc[i], ldst[i]);
#pragma unroll
        for (int i = 0; i < 8; ++i) gsrc[i] += 64;
        __syncthreads();

#pragma unroll
        for (int kh = 0; kh < 2; ++kh) {
            bf16x8 af[4], b1f[2], b2f[2];
#pragma unroll
            for (int mi = 0; mi < 4; ++mi)
                af[mi] = *(const bf16x8*)&As[(wm * 64 + mi * 16 + lrow) * 64 + ko[kh]];
#pragma unroll
            for (int ni = 0; ni < 2; ++ni) {
                b1f[ni] = *(const bf16x8*)&B1s[(wn * 32 + ni * 16 + lrow) * 64 + ko[kh]];
                b2f[ni] = *(const bf16x8*)&B2s[(wn * 32 + ni * 16 + lrow) * 64 + ko[kh]];
            }
#pragma unroll
            for (int mi = 0; mi < 4; ++mi)
#pragma unroll
                for (int ni = 0; ni < 2; ++ni) {
                    acc1[mi][ni] = __builtin_amdgcn_mfma_f32_16x16x32_bf16(
                        af[mi], b1f[ni], acc1[mi][ni], 0, 0, 0);
                    acc2[mi][ni] = __builtin_amdgcn_mfma_f32_16x16x32_bf16(
                        af[mi], b2f[ni], acc2[mi][ni], 0, 0, 0);
                }
        }
        __syncthreads();
    }

    // epilogue: h = silu(a1) * a3 -> bf16 h_ws[slot, n]
#pragma unroll
    for (int mi = 0; mi < 4; ++mi) {
#pragma unroll
        for (int r = 0; r < 4; ++r) {
            int mloc = wm * 64 + mi * 16 + quad * 4 + r;
            int slot = slots_s[mloc];
            if (slot >= 0) {
                unsigned short* hrow =
                    h_ws + (size_t)slot * HID + n0 + wn * 32 + lrow;
#pragma unroll
                for (int ni = 0; ni < 2; ++ni) {
                    float a1 = acc1[mi][ni][r], a3 = acc2[mi][ni][r];
                    float hv = (a1 / (1.f + __expf(-a1))) * a3;
                    hrow[ni * 16] = (unsigned short)(f2bf_u(hv) >> 16);
                }
            }
        }
    }
}

// ---------------------------------------------------------------------------
// ffn2: gathered GEMM y = h @ w2^T, scale by routing weight, PLAIN store to
// per-slot y_ws (each (slot,n) written by exactly one block). BK=64,
// swizzled like ffn1. C-tile 128 x 128. grid (8, 64, 8).
// ---------------------------------------------------------------------------
__global__ __launch_bounds__(256) void ffn2_k(
    const unsigned short* __restrict__ h_ws, const unsigned short* __restrict__ w2b,
    const int* __restrict__ cnt, const int* __restrict__ slot_list,
    const float* __restrict__ slot_w, float* __restrict__ y_ws)
{
    __shared__ unsigned short As[128 * 64];
    __shared__ unsigned short Bs[128 * 64];
    __shared__ int slots_s[128];
    __shared__ float wgt_s[128];

    const int e = blockIdx.z;
    const int cntE = cnt[e];
    const int m0 = blockIdx.y * 128;
    if (m0 >= cntE) return;
    const int n0 = blockIdx.x * 128;
    const int tid = threadIdx.x;
    const int wave = tid >> 6, lane = tid & 63;

    if (tid < 128) {
        int idx = m0 + tid;
        int s = (idx < cntE) ? slot_list[e * T_TOK + idx] : -1;
        slots_s[tid] = s;
        wgt_s[tid] = (s >= 0) ? slot_w[s] : 0.f;
    }
    __syncthreads();

    const int sub = lane >> 3, kq = lane & 7;
    const int qg = kq ^ sub;
    const unsigned short* gsrc[8];
    unsigned short* ldst[8];
    if (wave < 2) {
#pragma unroll
        for (int i = 0; i < 8; ++i) {
            int row = wave * 64 + i * 8 + sub;
            int slot = slots_s[row];
            int s = (slot >= 0) ? slot : 0;
            gsrc[i] = h_ws + (size_t)s * HID + qg * 8;
            ldst[i] = &As[(wave * 64 + i * 8) * 64];
        }
    } else {
#pragma unroll
        for (int i = 0; i < 8; ++i) {
            int row = (wave - 2) * 64 + i * 8 + sub;
            gsrc[i] = w2b + ((size_t)e * DIM + n0 + row) * HID + qg * 8;
            ldst[i] = &Bs[((wave - 2) * 64 + i * 8) * 64];
        }
    }

    const int wm = wave >> 1, wn = wave & 1;
    const int lrow = lane & 15, quad = lane >> 4;
    const int s_r = lrow & 7;
    const int ko[2] = { (quad ^ s_r) * 8, ((quad | 4) ^ s_r) * 8 };

    f32x4 acc[4][4];
    const f32x4 zf = {0.f, 0.f, 0.f, 0.f};
#pragma unroll
    for (int mi = 0; mi < 4; ++mi)
#pragma unroll
        for (int ni = 0; ni < 4; ++ni) acc[mi][ni] = zf;

    for (int k0 = 0; k0 < HID; k0 += 64) {
#pragma unroll
        for (int i = 0; i < 8; ++i) gl_lds16(gsrc[i], ldst[i]);
#pragma unroll
        for (int i = 0; i < 8; ++i) gsrc[i] += 64;
        __syncthreads();

#pragma unroll
        for (int kh = 0; kh < 2; ++kh) {
            bf16x8 af[4], bf[4];
#pragma unroll
            for (int mi = 0; mi < 4; ++mi)
                af[mi] = *(const bf16x8*)&As[(wm * 64 + mi * 16 + lrow) * 64 + ko[kh]];
#pragma unroll
            for (int ni = 0; ni < 4; ++ni)
                bf[ni] = *(const bf16x8*)&Bs[(wn * 64 + ni * 16 + lrow) * 64 + ko[kh]];
#pragma unroll
            for (int mi = 0; mi < 4; ++mi)
#pragma unroll
                for (int ni = 0; ni < 4; ++ni)
                    acc[mi][ni] = __builtin_amdgcn_mfma_f32_16x16x32_bf16(
                        af[mi], bf[ni], acc[mi][ni], 0, 0, 0);
        }
        __syncthreads();
    }

#pragma unroll
    for (int mi = 0; mi < 4; ++mi) {
#pragma unroll
        for (int r = 0; r < 4; ++r) {
            int mloc = wm * 64 + mi * 16 + quad * 4 + r;
            int slot = slots_s[mloc];
            if (slot >= 0) {
                float w = wgt_s[mloc];
                float* yrow = y_ws + (size_t)slot * DIM + n0 + wn * 64 + lrow;
#pragma unroll
                for (int ni = 0; ni < 4; ++ni)
                    yrow[ni * 16] = acc[mi][ni][r] * w;
            }
        }
    }
}

// ---------------------------------------------------------------------------
// combine: out[t] = y_ws[2t] + y_ws[2t+1]. One block per token row.
// ---------------------------------------------------------------------------
__global__ __launch_bounds__(256) void combine_k(
    const float* __restrict__ y_ws, float* __restrict__ out)
{
    const int t = blockIdx.x, i = threadIdx.x;
    const float4* a = (const float4*)(y_ws + (size_t)(2 * t) * DIM);
    const float4* b = (const float4*)(y_ws + (size_t)(2 * t + 1) * DIM);
    float4 va = a[i], vb = b[i];
    float4 o = { va.x + vb.x, va.y + vb.y, va.z + vb.z, va.w + vb.w };
    ((float4*)(out + (size_t)t * DIM))[i] = o;
}

// ---------------------------------------------------------------------------
// Workspace layout (bytes):
//   [0, 256)                 cnt[8]                (memset 0 per launch)
//   [256, +262144)           slot_list[8][8192]
//   [+262144, +65536)        slot_w[16384]
//   [327936, +92274688)      h_ws   bf16 [16384][2816]
//   [92602624, +16777216)    x_bf   bf16 [8192][1024]
//   [109379840, +46137344)   w1_bf  bf16 [8][2816][1024]
//   [155517184, +46137344)   w3_bf
//   [201654528, +46137344)   w2_bf  bf16 [8][1024][2816]
//   y_ws fp32 [16384][1024] (67.1 MB) OVERLAPS w1_bf/w3_bf at 109379840 —
//   w1_bf/w3_bf are dead once ffn1 completes; ffn2/combine run after.
//   total ~247.8 MB
// ---------------------------------------------------------------------------
extern "C" void kernel_launch(void* const* d_in, const int* in_sizes, int n_in,
                              void* d_out, int out_size, void* d_ws, size_t ws_size,
                              hipStream_t stream) {
    const float* x  = (const float*)d_in[0];
    const float* gw = (const float*)d_in[1];
    const float* w1 = (const float*)d_in[2];
    const float* w2 = (const float*)d_in[3];
    const float* w3 = (const float*)d_in[4];
    float* out = (float*)d_out;

    char* ws = (char*)d_ws;
    int*   cnt       = (int*)ws;
    int*   slot_list = (int*)(ws + 256);
    float* slot_w    = (float*)(ws + 256 + NEXP * T_TOK * 4);
    unsigned short* h_ws  = (unsigned short*)(ws + 327936);
    unsigned short* x_bf  = (unsigned short*)(ws + 92602624);
    unsigned short* w1_bf = (unsigned short*)(ws + 109379840);
    unsigned short* w3_bf = (unsigned short*)(ws + 155517184);
    unsigned short* w2_bf = (unsigned short*)(ws + 201654528);
    float* y_ws = (float*)(ws + 109379840);   // overlaps w1_bf/w3_bf (dead by then)

    hipMemsetAsync(cnt, 0, 256, stream);

    const int nx = T_TOK * DIM / 8;              // 1048576
    const int nw = NEXP * HID * DIM / 8;         // 2883584
    cvt_k<<<(nx + 255) / 256, 256, 0, stream>>>(x, x_bf, nx);
    cvt3_k<<<dim3((nw + 255) / 256, 3), 256, 0, stream>>>(
        w1, w3, w2, w1_bf, w3_bf, w2_bf, nw);

    router_k<<<T_TOK / 4, 256, 0, stream>>>(x, gw, cnt, slot_list, slot_w);
    ffn1_k<<<dim3(HID / 64, T_TOK / 128, NEXP), 256, 0, stream>>>(
        x_bf, w1_bf, w3_bf, cnt, slot_list, h_ws);
    ffn2_k<<<dim3(DIM / 128, T_TOK / 128, NEXP), 256, 0, stream>>>(
        h_ws, w2_bf, cnt, slot_list, slot_w, y_ws);
    combine_k<<<T_TOK, 256, 0, stream>>>(y_ws, out);
}